// Round 6
// baseline (301.590 us; speedup 1.0000x reference)
//
#include <hip/hip_runtime.h>
#include <hip/hip_bf16.h>

typedef __bf16 bf16_t;
typedef __attribute__((ext_vector_type(8))) __bf16 bf16x8;
typedef __attribute__((ext_vector_type(4))) __bf16 bf16x4;
typedef __attribute__((ext_vector_type(4))) float f32x4;
typedef __attribute__((ext_vector_type(4))) unsigned int uint4v;

#define QSCALE 0.1803368801111204f  /* 0.125 * log2(e) */

// async global->LDS, 16B per lane; LDS dst = wave-uniform base + lane*16
static __device__ inline void glds16(const bf16_t* g, bf16_t* l) {
    __builtin_amdgcn_global_load_lds(
        (__attribute__((address_space(1))) const void*)g,
        (__attribute__((address_space(3))) void*)l,
        16, 0, 0);
}

// raw hardware v_exp_f32 (input bounded — no libm range/denorm fixup needed)
static __device__ inline float hwexp2(float x) {
#if __has_builtin(__builtin_amdgcn_exp2f)
    return __builtin_amdgcn_exp2f(x);
#else
    float r;
    asm("v_exp_f32 %0, %1" : "=v"(r) : "v"(x));
    return r;
#endif
}

// pack two fp32 -> bf16x2 by truncation (top 16 bits), single v_perm_b32
static __device__ inline unsigned int pack_trunc(float lo, float hi) {
    return __builtin_amdgcn_perm(__builtin_bit_cast(unsigned int, hi),
                                 __builtin_bit_cast(unsigned int, lo),
                                 0x07060302u);
}

// bf16-truncate a f32 in place (value a bf16 would hold), stays f32
static __device__ inline float btrunc(float x) {
    return __builtin_bit_cast(float, __builtin_bit_cast(unsigned int, x) & 0xFFFF0000u);
}

// ---------------------------------------------------------------------------
// fp32 -> bf16 convert (qkv_w only; proj_w conversion fused into patch_gemm)
// ---------------------------------------------------------------------------
__global__ void cvt_kernel(const float* __restrict__ in, bf16_t* __restrict__ out, int n4) {
    int i = blockIdx.x * 256 + threadIdx.x;
    if (i < n4) {
        float4 v = ((const float4*)in)[i];
        bf16x4 o = {(bf16_t)v.x, (bf16_t)v.y, (bf16_t)v.z, (bf16_t)v.w};
        ((bf16x4*)out)[i] = o;
    }
}

// ---------------------------------------------------------------------------
// Patch-embed GEMM: tok[4096,768] = patches[4096,256] @ proj_w[768,256]^T + b
// ---------------------------------------------------------------------------
__global__ __launch_bounds__(256) void patch_gemm(const float* __restrict__ x,
                                                  const float* __restrict__ pw,
                                                  const float* __restrict__ pb,
                                                  float* __restrict__ tok) {
    const int bn = blockIdx.x;   // 12 embed tiles
    const int bm = blockIdx.y;   // 64 token tiles
    const int tid = threadIdx.x;

    __shared__ bf16_t At[64][264];
    __shared__ bf16_t Bt[64][264];

    #pragma unroll
    for (int t = 0; t < 16; t++) {
        int linear = tid + t * 256;
        int ml = linear >> 6;
        int kv = (linear & 63) << 2;
        int n = bm * 64 + ml;
        int pr = n >> 6, pc = n & 63;
        int i = kv >> 4, j = kv & 15;
        float4 v = *(const float4*)(x + (pr * 16 + i) * 1024 + pc * 16 + j);
        bf16x4 o = {(bf16_t)v.x, (bf16_t)v.y, (bf16_t)v.z, (bf16_t)v.w};
        *(bf16x4*)(&At[ml][kv]) = o;
    }
    #pragma unroll
    for (int t = 0; t < 8; t++) {
        int linear = tid + t * 256;
        int nl = linear >> 5;
        int kv = (linear & 31) << 3;
        const float* src = pw + (size_t)(bn * 64 + nl) * 256 + kv;
        float4 v0 = *(const float4*)(src);
        float4 v1 = *(const float4*)(src + 4);
        bf16x8 o = {(bf16_t)v0.x, (bf16_t)v0.y, (bf16_t)v0.z, (bf16_t)v0.w,
                    (bf16_t)v1.x, (bf16_t)v1.y, (bf16_t)v1.z, (bf16_t)v1.w};
        *(bf16x8*)(&Bt[nl][kv]) = o;
    }
    __syncthreads();

    const int lane = tid & 63, wid = tid >> 6, ln = lane & 15, quad = lane >> 4;
    f32x4 acc[4];
    #pragma unroll
    for (int s = 0; s < 4; s++) acc[s] = {0.f, 0.f, 0.f, 0.f};

    #pragma unroll
    for (int kk = 0; kk < 8; kk++) {
        bf16x8 af = *(const bf16x8*)(&At[wid * 16 + ln][kk * 32 + quad * 8]);
        #pragma unroll
        for (int s = 0; s < 4; s++) {
            bf16x8 bfr = *(const bf16x8*)(&Bt[s * 16 + ln][kk * 32 + quad * 8]);
            acc[s] = __builtin_amdgcn_mfma_f32_16x16x32_bf16(af, bfr, acc[s], 0, 0, 0);
        }
    }

    #pragma unroll
    for (int s = 0; s < 4; s++) {
        int e = bn * 64 + s * 16 + ln;
        float bias = pb[e];
        #pragma unroll
        for (int r = 0; r < 4; r++) {
            int m = bm * 64 + wid * 16 + quad * 4 + r;
            tok[(size_t)m * 768 + e] = acc[s][r] + bias;
        }
    }
}

// ---------------------------------------------------------------------------
// LayerNorm per token (768), fp32 stats, bf16 out.
// ---------------------------------------------------------------------------
__global__ __launch_bounds__(256) void ln_kernel(const float* __restrict__ tok,
                                                 const float* __restrict__ g,
                                                 const float* __restrict__ b,
                                                 bf16_t* __restrict__ out) {
    const int n = blockIdx.x;
    const int tid = threadIdx.x;
    const float* row = tok + (size_t)n * 768;
    float x0 = row[tid], x1 = row[tid + 256], x2 = row[tid + 512];
    float s = x0 + x1 + x2;
    float s2 = x0 * x0 + x1 * x1 + x2 * x2;
    #pragma unroll
    for (int off = 32; off; off >>= 1) {
        s += __shfl_xor(s, off);
        s2 += __shfl_xor(s2, off);
    }
    __shared__ float ws1[4], ws2[4];
    int wid = tid >> 6;
    if ((tid & 63) == 0) { ws1[wid] = s; ws2[wid] = s2; }
    __syncthreads();
    s = ws1[0] + ws1[1] + ws1[2] + ws1[3];
    s2 = ws2[0] + ws2[1] + ws2[2] + ws2[3];
    float mu = s * (1.f / 768.f);
    float var = s2 * (1.f / 768.f) - mu * mu;
    float r = rsqrtf(var + 1e-6f);
    bf16_t* orow = out + (size_t)n * 768;
    orow[tid]       = (bf16_t)((x0 - mu) * r * g[tid]       + b[tid]);
    orow[tid + 256] = (bf16_t)((x1 - mu) * r * g[tid + 256] + b[tid + 256]);
    orow[tid + 512] = (bf16_t)((x2 - mu) * r * g[tid + 512] + b[tid + 512]);
}

// ---------------------------------------------------------------------------
// QKV GEMM: bn-fastest grid (36, 32), 128(M)x64(N) tile, BK=64, async dbuf
// glds16 staging with XOR-swizzled LDS. bn: 0..11 = q, 12..23 = k, 24..35 = v.
// ---------------------------------------------------------------------------
__global__ __launch_bounds__(256) void qkv_gemm(const bf16_t* __restrict__ tokb,
                                                const bf16_t* __restrict__ wq,
                                                bf16_t* __restrict__ qb,
                                                bf16_t* __restrict__ kswz,
                                                bf16_t* __restrict__ vswz) {
    const int bn = blockIdx.x;   // 36 n-tiles (64 cols = one head of q/k/v)
    const int bm = blockIdx.y;   // 32 m-tiles (128 tokens)
    const int tid = threadIdx.x;
    const int wid = tid >> 6, lane = tid & 63;
    const int ln = lane & 15, quad = lane >> 4;
    const int wm = wid & 1, wn = wid >> 1;

    __shared__ bf16_t Asw[2][8192];   // 128 rows x 8 chunks x 8 bf16
    __shared__ bf16_t Bsw[2][4096];   // 64 rows x 8 chunks

    f32x4 acc[4][2];
    #pragma unroll
    for (int sm = 0; sm < 4; sm++)
        #pragma unroll
        for (int sn = 0; sn < 2; sn++) acc[sm][sn] = {0.f, 0.f, 0.f, 0.f};

    // staging: per wave, A chunks [wid*256, +256) (4 issues), B [wid*128, +128) (2)
    auto stage = [&](int kb0, int buf) {
        #pragma unroll
        for (int i = 0; i < 4; i++) {
            int L = wid * 256 + i * 64 + lane;
            int r = L >> 3, c = L & 7;
            int gc = c ^ (r & 7);
            glds16(tokb + (size_t)(bm * 128 + r) * 768 + kb0 + gc * 8,
                   Asw[buf] + (wid * 256 + i * 64) * 8);
        }
        #pragma unroll
        for (int i = 0; i < 2; i++) {
            int L = wid * 128 + i * 64 + lane;
            int r = L >> 3, c = L & 7;
            int gc = c ^ (r & 7);
            glds16(wq + (size_t)(bn * 64 + r) * 768 + kb0 + gc * 8,
                   Bsw[buf] + (wid * 128 + i * 64) * 8);
        }
    };

    auto compute = [&](const bf16_t* Ab, const bf16_t* Bb) {
        #pragma unroll
        for (int kk = 0; kk < 2; kk++) {
            const int c = (kk * 4 + quad) ^ (ln & 7);
            bf16x8 af[4], bfr[2];
            #pragma unroll
            for (int sm = 0; sm < 4; sm++) {
                int row = wm * 64 + sm * 16 + ln;
                af[sm] = *(const bf16x8*)(Ab + (row * 8 + c) * 8);
            }
            #pragma unroll
            for (int sn = 0; sn < 2; sn++) {
                int row = wn * 32 + sn * 16 + ln;
                bfr[sn] = *(const bf16x8*)(Bb + (row * 8 + c) * 8);
            }
            #pragma unroll
            for (int sm = 0; sm < 4; sm++)
                #pragma unroll
                for (int sn = 0; sn < 2; sn++)
                    acc[sm][sn] = __builtin_amdgcn_mfma_f32_16x16x32_bf16(af[sm], bfr[sn], acc[sm][sn], 0, 0, 0);
        }
    };

    stage(0, 0);

    for (int s = 0; s < 12; s += 2) {
        __builtin_amdgcn_s_barrier();                 // prev reads of buf1 done
        stage((s + 1) * 64, 1);
        __builtin_amdgcn_s_waitcnt(0x0F76);           // vmcnt(6): buf0 resident
        __builtin_amdgcn_s_barrier();
        compute(Asw[0], Bsw[0]);
        __builtin_amdgcn_s_barrier();                 // prev reads of buf0 done
        if (s + 2 < 12) {
            stage((s + 2) * 64, 0);
            __builtin_amdgcn_s_waitcnt(0x0F76);       // vmcnt(6)
        } else {
            __builtin_amdgcn_s_waitcnt(0x0F70);       // vmcnt(0)
        }
        __builtin_amdgcn_s_barrier();
        compute(Asw[1], Bsw[1]);
    }

    const int sidx = bn / 12;                  // 0=q 1=k 2=v (block-uniform)
    const int head = bn % 12;
    #pragma unroll
    for (int sn = 0; sn < 2; sn++) {
        int dc = wn * 32 + sn * 16 + ln;       // 0..63 within head
        #pragma unroll
        for (int sm = 0; sm < 4; sm++) {
            #pragma unroll
            for (int r = 0; r < 4; r++) {
                int m = bm * 128 + wm * 64 + sm * 16 + quad * 4 + r;   // token = key
                float v = acc[sm][sn][r];
                if (sidx == 0) {
                    qb[((size_t)(head * 4096 + m)) * 64 + dc] = (bf16_t)(v * QSCALE);
                } else if (sidx == 1) {
                    bf16_t val = (bf16_t)v;
                    int kt = m >> 6, sb = (m >> 4) & 3, lnk = m & 15;
                    int half = dc >> 5, quadk = (dc >> 3) & 3, j = dc & 7;
                    int l = quadk * 16 + lnk;
                    kswz[((size_t)(head * 64 + kt)) * 4096 + sb * 1024 + half * 512 + l * 8 + j] = val;
                } else {
                    bf16_t val = (bf16_t)v;
                    int kt = m >> 6, keyl = m & 63;
                    int sblk = keyl >> 4;
                    int mm = sblk >> 1, tb = sblk & 1;
                    int w16 = keyl & 15, qv = w16 >> 2, jj = w16 & 3;
                    int jp = tb * 4 + jj;
                    int db = dc >> 4, lnv = dc & 15;
                    int l = qv * 16 + lnv;
                    vswz[((size_t)(head * 64 + kt)) * 4096 + ((mm * 4 + db) * 64 + l) * 8 + jp] = val;
                }
            }
        }
    }
}

// ---------------------------------------------------------------------------
// Attention v7: v6 (barrier-free, global-direct K/V, VALU l-sum) with the
// register footprint trimmed under the 3-waves/SIMD step.
//
// Occupancy-gate theory: gfx950 unified VGPR+AGPR budget, 512 regs/SIMD pool
// -> 3 waves need total <= ~170. v6: 108 VGPR + 64 AGPR (accO) = 172 -> 2
// waves/SIMD cap -> matrix pipe starves during each wave's exp/pack phase
// (all six prior structures pinned at 60-65us, MFMA+VALU ~75% combined).
// Evidence VGPR_Count excludes AGPR: v4's (256,3) squeezed to "84 VGPR" yet
// spilled massively -- only consistent if AGPRs were eating the budget.
// v7: drop the V prefetch buffer (-16 regs): K stays double-buffered (kA/kB),
// V single-buffered, loaded at the top of each half-tile so QK+exp (~300cyc)
// covers its L2 latency before first PV use. Total ~156 <= 168 ->
// __launch_bounds__(256,3) now FITS (no v4-style spill).
// ---------------------------------------------------------------------------
__global__ __launch_bounds__(256, 3) void attn_partial(const bf16_t* __restrict__ qbuf,
                                                       const bf16_t* __restrict__ kswz,
                                                       const bf16_t* __restrict__ vswz,
                                                       float* __restrict__ raw0,
                                                       float* __restrict__ raw1,
                                                       float* __restrict__ l_part) {
    const int h = blockIdx.y;
    const int chunk = blockIdx.z;
    const int tid = threadIdx.x;
    const int wid = tid >> 6;           // 0..3
    const int lane = tid & 63;
    const int ln = lane & 15, quad = lane >> 4;
    const int qh = wid & 1;             // which 64-query half
    const int kh = wid >> 1;            // which 16-tile half (block split-K)
    const int q0 = blockIdx.x * 128;

    // combine scratch only: [128][68] f32 (34816B) + l[128] (512B)
    __shared__ __align__(16) float COMB[128 * 68 + 128];

    // Q B-frags for this wave's four 16-query groups (64 queries/wave)
    bf16x8 qf[4][2];
    #pragma unroll
    for (int g = 0; g < 4; g++) {
        const int q0g = q0 + qh * 64 + g * 16;
        const bf16_t* qrow = qbuf + ((size_t)h * 4096 + q0g + ln) * 64;
        qf[g][0] = *(const bf16x8*)(qrow + quad * 8);
        qf[g][1] = *(const bf16x8*)(qrow + 32 + quad * 8);
    }

    // this pair's 16-tile (= 32 half-tile) sub-chunk
    const bf16_t* kg = kswz + (size_t)h * 64 * 4096 + (size_t)(chunk * 32 + kh * 16) * 4096;
    const bf16_t* vg = vswz + (size_t)h * 64 * 4096 + (size_t)(chunk * 32 + kh * 16) * 4096;

    f32x4 accO[4][4];
    float lsum[4];
    #pragma unroll
    for (int g = 0; g < 4; g++) {
        lsum[g] = 0.f;
        #pragma unroll
        for (int d = 0; d < 4; d++) accO[g][d] = {0.f, 0.f, 0.f, 0.f};
    }

    bf16x8 kA[4], kB[4], vS[4];

    auto loadK = [&](int ht, bf16x8* kf) {
        const bf16_t* kp = kg + (size_t)ht * 2048 + lane * 8;
        #pragma unroll
        for (int i = 0; i < 4; i++) kf[i] = *(const bf16x8*)(kp + i * 512);
    };
    auto loadV = [&](int ht) {
        const bf16_t* vp = vg + (size_t)ht * 2048 + lane * 8;
        #pragma unroll
        for (int i = 0; i < 4; i++) vS[i] = *(const bf16x8*)(vp + i * 512);
    };

    // one 32-key half-tile: K from kf, V from vS (loaded this iteration)
    auto computeF = [&](const bf16x8* kf) {
        #pragma unroll
        for (int g = 0; g < 4; g++) {
            f32x4 z = {0.f, 0.f, 0.f, 0.f};
            f32x4 SA = __builtin_amdgcn_mfma_f32_16x16x32_bf16(kf[0], qf[g][0], z, 0, 0, 0);
            SA = __builtin_amdgcn_mfma_f32_16x16x32_bf16(kf[1], qf[g][1], SA, 0, 0, 0);
            f32x4 SB = __builtin_amdgcn_mfma_f32_16x16x32_bf16(kf[2], qf[g][0], z, 0, 0, 0);
            SB = __builtin_amdgcn_mfma_f32_16x16x32_bf16(kf[3], qf[g][1], SB, 0, 0, 0);

            float e0 = hwexp2(SA[0]), e1 = hwexp2(SA[1]), e2 = hwexp2(SA[2]), e3 = hwexp2(SA[3]);
            float e4 = hwexp2(SB[0]), e5 = hwexp2(SB[1]), e6 = hwexp2(SB[2]), e7 = hwexp2(SB[3]);
            // l-sum of the bf16-truncated values (numerics match P truncation)
            lsum[g] += ((btrunc(e0) + btrunc(e1)) + (btrunc(e2) + btrunc(e3)))
                     + ((btrunc(e4) + btrunc(e5)) + (btrunc(e6) + btrunc(e7)));
            uint4v u = {pack_trunc(e0, e1), pack_trunc(e2, e3),
                        pack_trunc(e4, e5), pack_trunc(e6, e7)};
            bf16x8 pb = __builtin_bit_cast(bf16x8, u);
            #pragma unroll
            for (int db = 0; db < 4; db++)
                accO[g][db] = __builtin_amdgcn_mfma_f32_16x16x32_bf16(vS[db], pb, accO[g][db], 0, 0, 0);
        }
    };

    loadK(0, kA);

    for (int ht = 0; ht < 32; ht += 2) {
        loadV(ht);                      // V for this half-tile: latency covered
        loadK(ht + 1, kB);              // by QK+exp before first PV use
        computeF(kA);
        loadV(ht + 1);
        if (ht + 2 < 32) loadK(ht + 2, kA);
        computeF(kB);
    }

    // reduce lsum over the 4 quad-lanes (key sub-rows): lanes ln+16*quad
    #pragma unroll
    for (int g = 0; g < 4; g++) {
        lsum[g] += __shfl_xor(lsum[g], 16);
        lsum[g] += __shfl_xor(lsum[g], 32);
    }

    // ---- block-internal split-K combine over LDS ----
    float* comb  = COMB;              // [128][68] f32
    float* combl = COMB + 128 * 68;   // 128 f32
    if (kh == 1) {
        #pragma unroll
        for (int g = 0; g < 4; g++) {
            const int lq = qh * 64 + g * 16 + ln;
            #pragma unroll
            for (int db = 0; db < 4; db++)
                *(f32x4*)&comb[lq * 68 + db * 16 + quad * 4] = accO[g][db];
            if (quad == 0) combl[lq] = lsum[g];
        }
    }
    __syncthreads();
    if (kh == 0) {
        float* base = chunk ? raw1 : raw0;
        #pragma unroll
        for (int g = 0; g < 4; g++) {
            const int lq = qh * 64 + g * 16 + ln;
            const int qg = q0 + lq;
            float ltot = lsum[g] + combl[lq];
            if (quad == 0) l_part[(size_t)chunk * 49152 + h * 4096 + qg] = ltot;
            float* op = base + (size_t)qg * 768 + h * 64 + quad * 4;
            #pragma unroll
            for (int db = 0; db < 4; db++) {
                f32x4 o = accO[g][db] + *(const f32x4*)&comb[lq * 68 + db * 16 + quad * 4];
                *(f32x4*)(op + db * 16) = o;
            }
        }
    }
}

// ---------------------------------------------------------------------------
// Normalize + combine: out[q,c] = (raw0[q,c] + raw1[q,c]) / (l0[h][q]+l1[h][q])
// raw1 aliases out (d_out scratch) — element-wise read-then-write, safe.
// ---------------------------------------------------------------------------
__global__ __launch_bounds__(256) void norm_kernel(const float* __restrict__ raw0,
                                                   const float* __restrict__ raw1,
                                                   const float* __restrict__ l_part,
                                                   float* __restrict__ out) {
    const int q = blockIdx.x;
    const int tid = threadIdx.x;
    __shared__ float linv[12];
    if (tid < 12)
        linv[tid] = 1.0f / (l_part[tid * 4096 + q] + l_part[49152 + tid * 4096 + q]);
    __syncthreads();
    #pragma unroll
    for (int t = 0; t < 3; t++) {
        int c = tid + t * 256;
        size_t idx = (size_t)q * 768 + c;
        out[idx] = (raw0[idx] + raw1[idx]) * linv[c >> 6];
    }
}

// ---------------------------------------------------------------------------
extern "C" void kernel_launch(void* const* d_in, const int* in_sizes, int n_in,
                              void* d_out, int out_size, void* d_ws, size_t ws_size,
                              hipStream_t stream) {
    const float* x      = (const float*)d_in[0];
    const float* proj_w = (const float*)d_in[1];
    const float* proj_b = (const float*)d_in[2];
    const float* ln_g   = (const float*)d_in[3];
    const float* ln_b   = (const float*)d_in[4];
    const float* qkv_w  = (const float*)d_in[5];
    float* out = (float*)d_out;

    char* ws = (char*)d_ws;
    float*  tok_pre = (float*)(ws + 0);              // 12,582,912 B (reused: raw0)
    bf16_t* tok_b   = (bf16_t*)(ws + 12582912);      //  6,291,456 B
    bf16_t* pw_b    = (bf16_t*)(ws + 18874368);      //    393,216 B (reused: l_part)
    bf16_t* qw_b    = (bf16_t*)(ws + 19267584);      //  3,538,944 B
    bf16_t* qbuf    = (bf16_t*)(ws + 22806528);      //  6,291,456 B
    bf16_t* kswz    = (bf16_t*)(ws + 29097984);      //  6,291,456 B
    bf16_t* vswz    = (bf16_t*)(ws + 35389440);      //  6,291,456 B (total ~41.7 MB)
    float*  raw0    = tok_pre;                       // dead after ln_kernel
    float*  raw1    = out;                           // d_out used as chunk-1 scratch
    float*  l_part  = (float*)pw_b;                  // never used as pw_b anymore

    cvt_kernel<<<1728, 256, 0, stream>>>(qkv_w, qw_b, 442368);
    patch_gemm<<<dim3(12, 64), 256, 0, stream>>>(x, proj_w, proj_b, tok_pre);
    ln_kernel<<<4096, 256, 0, stream>>>(tok_pre, ln_g, ln_b, tok_b);
    qkv_gemm<<<dim3(36, 32), 256, 0, stream>>>(tok_b, qw_b, qbuf, kswz, vswz);
    attn_partial<<<dim3(32, 12, 2), 256, 0, stream>>>(qbuf, kswz, vswz, raw0, raw1, l_part);
    norm_kernel<<<4096, 256, 0, stream>>>(raw0, raw1, l_part, out);
}

// Round 7
// 190.868 us; speedup vs baseline: 1.5801x; 1.5801x over previous
//
#include <hip/hip_runtime.h>
#include <hip/hip_bf16.h>

typedef __bf16 bf16_t;
typedef __attribute__((ext_vector_type(8))) __bf16 bf16x8;
typedef __attribute__((ext_vector_type(4))) __bf16 bf16x4;
typedef __attribute__((ext_vector_type(4))) float f32x4;
typedef __attribute__((ext_vector_type(4))) unsigned int uint4v;

#define QSCALE 0.1803368801111204f  /* 0.125 * log2(e) */

// async global->LDS, 16B per lane; LDS dst = wave-uniform base + lane*16
static __device__ inline void glds16(const bf16_t* g, bf16_t* l) {
    __builtin_amdgcn_global_load_lds(
        (__attribute__((address_space(1))) const void*)g,
        (__attribute__((address_space(3))) void*)l,
        16, 0, 0);
}

// raw hardware v_exp_f32 (input bounded — no libm range/denorm fixup needed)
static __device__ inline float hwexp2(float x) {
#if __has_builtin(__builtin_amdgcn_exp2f)
    return __builtin_amdgcn_exp2f(x);
#else
    float r;
    asm("v_exp_f32 %0, %1" : "=v"(r) : "v"(x));
    return r;
#endif
}

// pack two fp32 -> bf16x2 by truncation (top 16 bits), single v_perm_b32
static __device__ inline unsigned int pack_trunc(float lo, float hi) {
    return __builtin_amdgcn_perm(__builtin_bit_cast(unsigned int, hi),
                                 __builtin_bit_cast(unsigned int, lo),
                                 0x07060302u);
}

// ---------------------------------------------------------------------------
// fp32 -> bf16 convert (qkv_w only; proj_w conversion fused into patch_gemm)
// ---------------------------------------------------------------------------
__global__ void cvt_kernel(const float* __restrict__ in, bf16_t* __restrict__ out, int n4) {
    int i = blockIdx.x * 256 + threadIdx.x;
    if (i < n4) {
        float4 v = ((const float4*)in)[i];
        bf16x4 o = {(bf16_t)v.x, (bf16_t)v.y, (bf16_t)v.z, (bf16_t)v.w};
        ((bf16x4*)out)[i] = o;
    }
}

// ---------------------------------------------------------------------------
// Patch-embed GEMM: tok[4096,768] = patches[4096,256] @ proj_w[768,256]^T + b
// ---------------------------------------------------------------------------
__global__ __launch_bounds__(256) void patch_gemm(const float* __restrict__ x,
                                                  const float* __restrict__ pw,
                                                  const float* __restrict__ pb,
                                                  float* __restrict__ tok) {
    const int bn = blockIdx.x;   // 12 embed tiles
    const int bm = blockIdx.y;   // 64 token tiles
    const int tid = threadIdx.x;

    __shared__ bf16_t At[64][264];
    __shared__ bf16_t Bt[64][264];

    #pragma unroll
    for (int t = 0; t < 16; t++) {
        int linear = tid + t * 256;
        int ml = linear >> 6;
        int kv = (linear & 63) << 2;
        int n = bm * 64 + ml;
        int pr = n >> 6, pc = n & 63;
        int i = kv >> 4, j = kv & 15;
        float4 v = *(const float4*)(x + (pr * 16 + i) * 1024 + pc * 16 + j);
        bf16x4 o = {(bf16_t)v.x, (bf16_t)v.y, (bf16_t)v.z, (bf16_t)v.w};
        *(bf16x4*)(&At[ml][kv]) = o;
    }
    #pragma unroll
    for (int t = 0; t < 8; t++) {
        int linear = tid + t * 256;
        int nl = linear >> 5;
        int kv = (linear & 31) << 3;
        const float* src = pw + (size_t)(bn * 64 + nl) * 256 + kv;
        float4 v0 = *(const float4*)(src);
        float4 v1 = *(const float4*)(src + 4);
        bf16x8 o = {(bf16_t)v0.x, (bf16_t)v0.y, (bf16_t)v0.z, (bf16_t)v0.w,
                    (bf16_t)v1.x, (bf16_t)v1.y, (bf16_t)v1.z, (bf16_t)v1.w};
        *(bf16x8*)(&Bt[nl][kv]) = o;
    }
    __syncthreads();

    const int lane = tid & 63, wid = tid >> 6, ln = lane & 15, quad = lane >> 4;
    f32x4 acc[4];
    #pragma unroll
    for (int s = 0; s < 4; s++) acc[s] = {0.f, 0.f, 0.f, 0.f};

    #pragma unroll
    for (int kk = 0; kk < 8; kk++) {
        bf16x8 af = *(const bf16x8*)(&At[wid * 16 + ln][kk * 32 + quad * 8]);
        #pragma unroll
        for (int s = 0; s < 4; s++) {
            bf16x8 bfr = *(const bf16x8*)(&Bt[s * 16 + ln][kk * 32 + quad * 8]);
            acc[s] = __builtin_amdgcn_mfma_f32_16x16x32_bf16(af, bfr, acc[s], 0, 0, 0);
        }
    }

    #pragma unroll
    for (int s = 0; s < 4; s++) {
        int e = bn * 64 + s * 16 + ln;
        float bias = pb[e];
        #pragma unroll
        for (int r = 0; r < 4; r++) {
            int m = bm * 64 + wid * 16 + quad * 4 + r;
            tok[(size_t)m * 768 + e] = acc[s][r] + bias;
        }
    }
}

// ---------------------------------------------------------------------------
// LayerNorm per token (768), fp32 stats, bf16 out.
// ---------------------------------------------------------------------------
__global__ __launch_bounds__(256) void ln_kernel(const float* __restrict__ tok,
                                                 const float* __restrict__ g,
                                                 const float* __restrict__ b,
                                                 bf16_t* __restrict__ out) {
    const int n = blockIdx.x;
    const int tid = threadIdx.x;
    const float* row = tok + (size_t)n * 768;
    float x0 = row[tid], x1 = row[tid + 256], x2 = row[tid + 512];
    float s = x0 + x1 + x2;
    float s2 = x0 * x0 + x1 * x1 + x2 * x2;
    #pragma unroll
    for (int off = 32; off; off >>= 1) {
        s += __shfl_xor(s, off);
        s2 += __shfl_xor(s2, off);
    }
    __shared__ float ws1[4], ws2[4];
    int wid = tid >> 6;
    if ((tid & 63) == 0) { ws1[wid] = s; ws2[wid] = s2; }
    __syncthreads();
    s = ws1[0] + ws1[1] + ws1[2] + ws1[3];
    s2 = ws2[0] + ws2[1] + ws2[2] + ws2[3];
    float mu = s * (1.f / 768.f);
    float var = s2 * (1.f / 768.f) - mu * mu;
    float r = rsqrtf(var + 1e-6f);
    bf16_t* orow = out + (size_t)n * 768;
    orow[tid]       = (bf16_t)((x0 - mu) * r * g[tid]       + b[tid]);
    orow[tid + 256] = (bf16_t)((x1 - mu) * r * g[tid + 256] + b[tid + 256]);
    orow[tid + 512] = (bf16_t)((x2 - mu) * r * g[tid + 512] + b[tid + 512]);
}

// ---------------------------------------------------------------------------
// QKV GEMM: bn-fastest grid (36, 32), 128(M)x64(N) tile, BK=64, async dbuf
// glds16 staging with XOR-swizzled LDS. bn: 0..11 = q, 12..23 = k, 24..35 = v.
// ---------------------------------------------------------------------------
__global__ __launch_bounds__(256) void qkv_gemm(const bf16_t* __restrict__ tokb,
                                                const bf16_t* __restrict__ wq,
                                                bf16_t* __restrict__ qb,
                                                bf16_t* __restrict__ kswz,
                                                bf16_t* __restrict__ vswz) {
    const int bn = blockIdx.x;   // 36 n-tiles (64 cols = one head of q/k/v)
    const int bm = blockIdx.y;   // 32 m-tiles (128 tokens)
    const int tid = threadIdx.x;
    const int wid = tid >> 6, lane = tid & 63;
    const int ln = lane & 15, quad = lane >> 4;
    const int wm = wid & 1, wn = wid >> 1;

    __shared__ bf16_t Asw[2][8192];   // 128 rows x 8 chunks x 8 bf16
    __shared__ bf16_t Bsw[2][4096];   // 64 rows x 8 chunks

    f32x4 acc[4][2];
    #pragma unroll
    for (int sm = 0; sm < 4; sm++)
        #pragma unroll
        for (int sn = 0; sn < 2; sn++) acc[sm][sn] = {0.f, 0.f, 0.f, 0.f};

    // staging: per wave, A chunks [wid*256, +256) (4 issues), B [wid*128, +128) (2)
    auto stage = [&](int kb0, int buf) {
        #pragma unroll
        for (int i = 0; i < 4; i++) {
            int L = wid * 256 + i * 64 + lane;
            int r = L >> 3, c = L & 7;
            int gc = c ^ (r & 7);
            glds16(tokb + (size_t)(bm * 128 + r) * 768 + kb0 + gc * 8,
                   Asw[buf] + (wid * 256 + i * 64) * 8);
        }
        #pragma unroll
        for (int i = 0; i < 2; i++) {
            int L = wid * 128 + i * 64 + lane;
            int r = L >> 3, c = L & 7;
            int gc = c ^ (r & 7);
            glds16(wq + (size_t)(bn * 64 + r) * 768 + kb0 + gc * 8,
                   Bsw[buf] + (wid * 128 + i * 64) * 8);
        }
    };

    auto compute = [&](const bf16_t* Ab, const bf16_t* Bb) {
        #pragma unroll
        for (int kk = 0; kk < 2; kk++) {
            const int c = (kk * 4 + quad) ^ (ln & 7);
            bf16x8 af[4], bfr[2];
            #pragma unroll
            for (int sm = 0; sm < 4; sm++) {
                int row = wm * 64 + sm * 16 + ln;
                af[sm] = *(const bf16x8*)(Ab + (row * 8 + c) * 8);
            }
            #pragma unroll
            for (int sn = 0; sn < 2; sn++) {
                int row = wn * 32 + sn * 16 + ln;
                bfr[sn] = *(const bf16x8*)(Bb + (row * 8 + c) * 8);
            }
            #pragma unroll
            for (int sm = 0; sm < 4; sm++)
                #pragma unroll
                for (int sn = 0; sn < 2; sn++)
                    acc[sm][sn] = __builtin_amdgcn_mfma_f32_16x16x32_bf16(af[sm], bfr[sn], acc[sm][sn], 0, 0, 0);
        }
    };

    stage(0, 0);

    for (int s = 0; s < 12; s += 2) {
        __builtin_amdgcn_s_barrier();                 // prev reads of buf1 done
        stage((s + 1) * 64, 1);
        __builtin_amdgcn_s_waitcnt(0x0F76);           // vmcnt(6): buf0 resident
        __builtin_amdgcn_s_barrier();
        compute(Asw[0], Bsw[0]);
        __builtin_amdgcn_s_barrier();                 // prev reads of buf0 done
        if (s + 2 < 12) {
            stage((s + 2) * 64, 0);
            __builtin_amdgcn_s_waitcnt(0x0F76);       // vmcnt(6)
        } else {
            __builtin_amdgcn_s_waitcnt(0x0F70);       // vmcnt(0)
        }
        __builtin_amdgcn_s_barrier();
        compute(Asw[1], Bsw[1]);
    }

    const int sidx = bn / 12;                  // 0=q 1=k 2=v (block-uniform)
    const int head = bn % 12;
    #pragma unroll
    for (int sn = 0; sn < 2; sn++) {
        int dc = wn * 32 + sn * 16 + ln;       // 0..63 within head
        #pragma unroll
        for (int sm = 0; sm < 4; sm++) {
            #pragma unroll
            for (int r = 0; r < 4; r++) {
                int m = bm * 128 + wm * 64 + sm * 16 + quad * 4 + r;   // token = key
                float v = acc[sm][sn][r];
                if (sidx == 0) {
                    qb[((size_t)(head * 4096 + m)) * 64 + dc] = (bf16_t)(v * QSCALE);
                } else if (sidx == 1) {
                    bf16_t val = (bf16_t)v;
                    int kt = m >> 6, sb = (m >> 4) & 3, lnk = m & 15;
                    int half = dc >> 5, quadk = (dc >> 3) & 3, j = dc & 7;
                    int l = quadk * 16 + lnk;
                    kswz[((size_t)(head * 64 + kt)) * 4096 + sb * 1024 + half * 512 + l * 8 + j] = val;
                } else {
                    bf16_t val = (bf16_t)v;
                    int kt = m >> 6, keyl = m & 63;
                    int sblk = keyl >> 4;
                    int mm = sblk >> 1, tb = sblk & 1;
                    int w16 = keyl & 15, qv = w16 >> 2, jj = w16 & 3;
                    int jp = tb * 4 + jj;
                    int db = dc >> 4, lnv = dc & 15;
                    int l = qv * 16 + lnv;
                    vswz[((size_t)(head * 64 + kt)) * 4096 + ((mm * 4 + db) * 64 + l) * 8 + jp] = val;
                }
            }
        }
    }
}

// ---------------------------------------------------------------------------
// Attention v8: 32q/WAVE to unlock 4 waves/SIMD occupancy.
//
// Tension identified over v1-v7: 64q/wave needs ~172 regs (VGPR+AGPR unified)
// -> hard 2-waves/SIMD cap -> per-wave QK->exp->pack->PV chain exposed ->
// every structure pins at 60-65us (~2x the 31us MFMA floor). Forcing 3
// waves via launch_bounds spills catastrophically (v4: 381MB, v7: 521MB
// scratch writes). 32q/wave: qf 16 + accO 32(A) + accL 8(A) + transients
// ~= 120 total -> ~17 waves/CU by regs. LDS traffic doubles per FLOP
// (~1.6GB ~= 30us) but now overlaps ACROSS waves with MFMA (31us).
// v8: 64-query blocks, grid (64,12,2)=1536 (6 blocks/CU, smoother than
// 768@3), 4 waves = qh(2) x kh(2) split-K, v5's half-tile glds16 dbuf
// (32KB staging, combine [64][68] f32 unioned inside), plain
// __launch_bounds__(256) -- no min-wave request (spill tripwire armed:
// WRITE_SIZE must stay ~25MB).
// ---------------------------------------------------------------------------
__global__ __launch_bounds__(256) void attn_partial(const bf16_t* __restrict__ qbuf,
                                                    const bf16_t* __restrict__ kswz,
                                                    const bf16_t* __restrict__ vswz,
                                                    float* __restrict__ raw0,
                                                    float* __restrict__ raw1,
                                                    float* __restrict__ l_part) {
    const int h = blockIdx.y;
    const int chunk = blockIdx.z;
    const int tid = threadIdx.x;
    const int wid = tid >> 6;           // 0..3
    const int lane = tid & 63;
    const int ln = lane & 15, quad = lane >> 4;
    const int qh = wid & 1;             // which 32-query half of the 64q block
    const int kh = wid >> 1;            // which 16-tile key half (block split-K)
    const int q0 = blockIdx.x * 64;

    // staging: K [2 kh][2 buf][2048] at 0, V same at +16384 (32KB total);
    // combine view after syncthreads: [64][68] f32 + l[64] = 17.7KB (fits).
    __shared__ __align__(16) char RAW[32768];
    bf16_t* Kst = (bf16_t*)RAW;
    bf16_t* Vst = (bf16_t*)(RAW + 16384);

    // Q B-frags for this wave's two 16-query groups (32 queries/wave)
    bf16x8 qf[2][2];
    #pragma unroll
    for (int g = 0; g < 2; g++) {
        const int q0g = q0 + qh * 32 + g * 16;
        const bf16_t* qrow = qbuf + ((size_t)h * 4096 + q0g + ln) * 64;
        qf[g][0] = *(const bf16x8*)(qrow + quad * 8);
        qf[g][1] = *(const bf16x8*)(qrow + 32 + quad * 8);
    }

    // all-ones A fragment for the l row-sum MFMA
    bf16x8 ones;
    #pragma unroll
    for (int i = 0; i < 8; i++) ones[i] = (bf16_t)1.0f;

    // this pair's 16-tile (= 32 half-tile) key sub-chunk
    const bf16_t* kg = kswz + (size_t)h * 64 * 4096 + (size_t)(chunk * 32 + kh * 16) * 4096;
    const bf16_t* vg = vswz + (size_t)h * 64 * 4096 + (size_t)(chunk * 32 + kh * 16) * 4096;

    f32x4 accO[2][4];
    f32x4 accL[2];
    #pragma unroll
    for (int g = 0; g < 2; g++) {
        accL[g] = {0.f, 0.f, 0.f, 0.f};
        #pragma unroll
        for (int d = 0; d < 4; d++) accO[g][d] = {0.f, 0.f, 0.f, 0.f};
    }

    // stage one 4KB K + 4KB V half-tile (32 keys) per kh pair; the pair's
    // two waves (qh) each cover half: 2 K + 2 V glds16 per wave
    auto stage = [&](int ht, int buf) {
        const bf16_t* kt_g = kg + (size_t)ht * 2048;
        const bf16_t* vt_g = vg + (size_t)ht * 2048;
        bf16_t* kl = Kst + (kh * 2 + buf) * 2048 + qh * 1024;
        bf16_t* vl = Vst + (kh * 2 + buf) * 2048 + qh * 1024;
        #pragma unroll
        for (int i = 0; i < 2; i++) {
            glds16(kt_g + qh * 1024 + i * 512 + lane * 8, kl + i * 512);
            glds16(vt_g + qh * 1024 + i * 512 + lane * 8, vl + i * 512);
        }
    };

    // one 32-key half-tile: Kb/Vb are 2048-elem LDS buffers
    auto compute = [&](const bf16_t* Kb, const bf16_t* Vb) {
        bf16x8 vf[4];
        #pragma unroll
        for (int db = 0; db < 4; db++)
            vf[db] = *(const bf16x8*)(Vb + db * 512 + lane * 8);
        bf16x8 kfa0 = *(const bf16x8*)(Kb + lane * 8);
        bf16x8 kfa1 = *(const bf16x8*)(Kb + 512 + lane * 8);
        bf16x8 kfb0 = *(const bf16x8*)(Kb + 1024 + lane * 8);
        bf16x8 kfb1 = *(const bf16x8*)(Kb + 1536 + lane * 8);
        #pragma unroll
        for (int g = 0; g < 2; g++) {
            f32x4 z = {0.f, 0.f, 0.f, 0.f};
            f32x4 SA = __builtin_amdgcn_mfma_f32_16x16x32_bf16(kfa0, qf[g][0], z, 0, 0, 0);
            SA = __builtin_amdgcn_mfma_f32_16x16x32_bf16(kfa1, qf[g][1], SA, 0, 0, 0);
            f32x4 SB = __builtin_amdgcn_mfma_f32_16x16x32_bf16(kfb0, qf[g][0], z, 0, 0, 0);
            SB = __builtin_amdgcn_mfma_f32_16x16x32_bf16(kfb1, qf[g][1], SB, 0, 0, 0);

            float e0 = hwexp2(SA[0]), e1 = hwexp2(SA[1]), e2 = hwexp2(SA[2]), e3 = hwexp2(SA[3]);
            float e4 = hwexp2(SB[0]), e5 = hwexp2(SB[1]), e6 = hwexp2(SB[2]), e7 = hwexp2(SB[3]);
            uint4v u = {pack_trunc(e0, e1), pack_trunc(e2, e3),
                        pack_trunc(e4, e5), pack_trunc(e6, e7)};
            bf16x8 pb = __builtin_bit_cast(bf16x8, u);
            accL[g] = __builtin_amdgcn_mfma_f32_16x16x32_bf16(ones, pb, accL[g], 0, 0, 0);
            #pragma unroll
            for (int db = 0; db < 4; db++)
                accO[g][db] = __builtin_amdgcn_mfma_f32_16x16x32_bf16(vf[db], pb, accO[g][db], 0, 0, 0);
        }
    };

    stage(0, 0);

    const bf16_t* K0 = Kst + (kh * 2 + 0) * 2048;
    const bf16_t* V0 = Vst + (kh * 2 + 0) * 2048;
    const bf16_t* K1 = Kst + (kh * 2 + 1) * 2048;
    const bf16_t* V1 = Vst + (kh * 2 + 1) * 2048;

    for (int ht = 0; ht < 32; ht += 2) {
        __builtin_amdgcn_s_barrier();                 // prev reads of buf1 done
        stage(ht + 1, 1);
        __builtin_amdgcn_s_waitcnt(0x0F74);           // vmcnt(4): half-tile ht resident
        __builtin_amdgcn_s_barrier();
        compute(K0, V0);
        __builtin_amdgcn_s_barrier();                 // prev reads of buf0 done
        if (ht + 2 < 32) {
            stage(ht + 2, 0);
            __builtin_amdgcn_s_waitcnt(0x0F74);       // vmcnt(4)
        } else {
            __builtin_amdgcn_s_waitcnt(0x0F70);       // vmcnt(0)
        }
        __builtin_amdgcn_s_barrier();
        compute(K1, V1);
    }

    // ---- block-internal split-K combine over LDS ----
    __syncthreads();   // all K/V reads done; RAW reusable
    float* comb  = (float*)RAW;               // [64][68] f32, 17408 B
    float* combl = (float*)(RAW + 17408);     // 64 f32
    if (kh == 1) {
        #pragma unroll
        for (int g = 0; g < 2; g++) {
            const int lq = qh * 32 + g * 16 + ln;
            #pragma unroll
            for (int db = 0; db < 4; db++)
                *(f32x4*)&comb[lq * 68 + db * 16 + quad * 4] = accO[g][db];
            if (quad == 0) combl[lq] = accL[g][0];
        }
    }
    __syncthreads();
    if (kh == 0) {
        float* base = chunk ? raw1 : raw0;
        #pragma unroll
        for (int g = 0; g < 2; g++) {
            const int lq = qh * 32 + g * 16 + ln;
            const int qg = q0 + lq;
            // every lane's accL[g][0] holds l[q=ln] (rows identical for ones-A)
            float lsum = accL[g][0] + combl[lq];
            if (quad == 0) l_part[(size_t)chunk * 49152 + h * 4096 + qg] = lsum;
            float* op = base + (size_t)qg * 768 + h * 64 + quad * 4;
            #pragma unroll
            for (int db = 0; db < 4; db++) {
                f32x4 o = accO[g][db] + *(const f32x4*)&comb[lq * 68 + db * 16 + quad * 4];
                *(f32x4*)(op + db * 16) = o;
            }
        }
    }
}

// ---------------------------------------------------------------------------
// Normalize + combine: out[q,c] = (raw0[q,c] + raw1[q,c]) / (l0[h][q]+l1[h][q])
// raw1 aliases out (d_out scratch) — element-wise read-then-write, safe.
// ---------------------------------------------------------------------------
__global__ __launch_bounds__(256) void norm_kernel(const float* __restrict__ raw0,
                                                   const float* __restrict__ raw1,
                                                   const float* __restrict__ l_part,
                                                   float* __restrict__ out) {
    const int q = blockIdx.x;
    const int tid = threadIdx.x;
    __shared__ float linv[12];
    if (tid < 12)
        linv[tid] = 1.0f / (l_part[tid * 4096 + q] + l_part[49152 + tid * 4096 + q]);
    __syncthreads();
    #pragma unroll
    for (int t = 0; t < 3; t++) {
        int c = tid + t * 256;
        size_t idx = (size_t)q * 768 + c;
        out[idx] = (raw0[idx] + raw1[idx]) * linv[c >> 6];
    }
}

// ---------------------------------------------------------------------------
extern "C" void kernel_launch(void* const* d_in, const int* in_sizes, int n_in,
                              void* d_out, int out_size, void* d_ws, size_t ws_size,
                              hipStream_t stream) {
    const float* x      = (const float*)d_in[0];
    const float* proj_w = (const float*)d_in[1];
    const float* proj_b = (const float*)d_in[2];
    const float* ln_g   = (const float*)d_in[3];
    const float* ln_b   = (const float*)d_in[4];
    const float* qkv_w  = (const float*)d_in[5];
    float* out = (float*)d_out;

    char* ws = (char*)d_ws;
    float*  tok_pre = (float*)(ws + 0);              // 12,582,912 B (reused: raw0)
    bf16_t* tok_b   = (bf16_t*)(ws + 12582912);      //  6,291,456 B
    bf16_t* pw_b    = (bf16_t*)(ws + 18874368);      //    393,216 B (reused: l_part)
    bf16_t* qw_b    = (bf16_t*)(ws + 19267584);      //  3,538,944 B
    bf16_t* qbuf    = (bf16_t*)(ws + 22806528);      //  6,291,456 B
    bf16_t* kswz    = (bf16_t*)(ws + 29097984);      //  6,291,456 B
    bf16_t* vswz    = (bf16_t*)(ws + 35389440);      //  6,291,456 B (total ~41.7 MB)
    float*  raw0    = tok_pre;                       // dead after ln_kernel
    float*  raw1    = out;                           // d_out used as chunk-1 scratch
    float*  l_part  = (float*)pw_b;                  // never used as pw_b anymore

    cvt_kernel<<<1728, 256, 0, stream>>>(qkv_w, qw_b, 442368);
    patch_gemm<<<dim3(12, 64), 256, 0, stream>>>(x, proj_w, proj_b, tok_pre);
    ln_kernel<<<4096, 256, 0, stream>>>(tok_pre, ln_g, ln_b, tok_b);
    qkv_gemm<<<dim3(36, 32), 256, 0, stream>>>(tok_b, qw_b, qbuf, kswz, vswz);
    attn_partial<<<dim3(64, 12, 2), 256, 0, stream>>>(qbuf, kswz, vswz, raw0, raw1, l_part);
    norm_kernel<<<4096, 256, 0, stream>>>(raw0, raw1, l_part, out);
}

// Round 8
// 176.947 us; speedup vs baseline: 1.7044x; 1.0787x over previous
//
#include <hip/hip_runtime.h>
#include <hip/hip_bf16.h>

typedef __bf16 bf16_t;
typedef __attribute__((ext_vector_type(8))) __bf16 bf16x8;
typedef __attribute__((ext_vector_type(4))) __bf16 bf16x4;
typedef __attribute__((ext_vector_type(4))) float f32x4;
typedef __attribute__((ext_vector_type(4))) unsigned int uint4v;

#define QSCALE 0.1803368801111204f  /* 0.125 * log2(e) */

// async global->LDS, 16B per lane; LDS dst = wave-uniform base + lane*16
static __device__ inline void glds16(const bf16_t* g, bf16_t* l) {
    __builtin_amdgcn_global_load_lds(
        (__attribute__((address_space(1))) const void*)g,
        (__attribute__((address_space(3))) void*)l,
        16, 0, 0);
}

// raw hardware v_exp_f32 (input bounded — no libm range/denorm fixup needed)
static __device__ inline float hwexp2(float x) {
#if __has_builtin(__builtin_amdgcn_exp2f)
    return __builtin_amdgcn_exp2f(x);
#else
    float r;
    asm("v_exp_f32 %0, %1" : "=v"(r) : "v"(x));
    return r;
#endif
}

// pack two fp32 -> bf16x2 by truncation (top 16 bits), single v_perm_b32
static __device__ inline unsigned int pack_trunc(float lo, float hi) {
    return __builtin_amdgcn_perm(__builtin_bit_cast(unsigned int, hi),
                                 __builtin_bit_cast(unsigned int, lo),
                                 0x07060302u);
}

// ---------------------------------------------------------------------------
// fp32 -> bf16 convert (qkv_w only; proj_w conversion fused into patch_gemm)
// ---------------------------------------------------------------------------
__global__ void cvt_kernel(const float* __restrict__ in, bf16_t* __restrict__ out, int n4) {
    int i = blockIdx.x * 256 + threadIdx.x;
    if (i < n4) {
        float4 v = ((const float4*)in)[i];
        bf16x4 o = {(bf16_t)v.x, (bf16_t)v.y, (bf16_t)v.z, (bf16_t)v.w};
        ((bf16x4*)out)[i] = o;
    }
}

// ---------------------------------------------------------------------------
// Patch-embed GEMM: tok[4096,768] = patches[4096,256] @ proj_w[768,256]^T + b
// ---------------------------------------------------------------------------
__global__ __launch_bounds__(256) void patch_gemm(const float* __restrict__ x,
                                                  const float* __restrict__ pw,
                                                  const float* __restrict__ pb,
                                                  float* __restrict__ tok) {
    const int bn = blockIdx.x;   // 12 embed tiles
    const int bm = blockIdx.y;   // 64 token tiles
    const int tid = threadIdx.x;

    __shared__ bf16_t At[64][264];
    __shared__ bf16_t Bt[64][264];

    #pragma unroll
    for (int t = 0; t < 16; t++) {
        int linear = tid + t * 256;
        int ml = linear >> 6;
        int kv = (linear & 63) << 2;
        int n = bm * 64 + ml;
        int pr = n >> 6, pc = n & 63;
        int i = kv >> 4, j = kv & 15;
        float4 v = *(const float4*)(x + (pr * 16 + i) * 1024 + pc * 16 + j);
        bf16x4 o = {(bf16_t)v.x, (bf16_t)v.y, (bf16_t)v.z, (bf16_t)v.w};
        *(bf16x4*)(&At[ml][kv]) = o;
    }
    #pragma unroll
    for (int t = 0; t < 8; t++) {
        int linear = tid + t * 256;
        int nl = linear >> 5;
        int kv = (linear & 31) << 3;
        const float* src = pw + (size_t)(bn * 64 + nl) * 256 + kv;
        float4 v0 = *(const float4*)(src);
        float4 v1 = *(const float4*)(src + 4);
        bf16x8 o = {(bf16_t)v0.x, (bf16_t)v0.y, (bf16_t)v0.z, (bf16_t)v0.w,
                    (bf16_t)v1.x, (bf16_t)v1.y, (bf16_t)v1.z, (bf16_t)v1.w};
        *(bf16x8*)(&Bt[nl][kv]) = o;
    }
    __syncthreads();

    const int lane = tid & 63, wid = tid >> 6, ln = lane & 15, quad = lane >> 4;
    f32x4 acc[4];
    #pragma unroll
    for (int s = 0; s < 4; s++) acc[s] = {0.f, 0.f, 0.f, 0.f};

    #pragma unroll
    for (int kk = 0; kk < 8; kk++) {
        bf16x8 af = *(const bf16x8*)(&At[wid * 16 + ln][kk * 32 + quad * 8]);
        #pragma unroll
        for (int s = 0; s < 4; s++) {
            bf16x8 bfr = *(const bf16x8*)(&Bt[s * 16 + ln][kk * 32 + quad * 8]);
            acc[s] = __builtin_amdgcn_mfma_f32_16x16x32_bf16(af, bfr, acc[s], 0, 0, 0);
        }
    }

    #pragma unroll
    for (int s = 0; s < 4; s++) {
        int e = bn * 64 + s * 16 + ln;
        float bias = pb[e];
        #pragma unroll
        for (int r = 0; r < 4; r++) {
            int m = bm * 64 + wid * 16 + quad * 4 + r;
            tok[(size_t)m * 768 + e] = acc[s][r] + bias;
        }
    }
}

// ---------------------------------------------------------------------------
// LayerNorm per token (768), fp32 stats, bf16 out.
// ---------------------------------------------------------------------------
__global__ __launch_bounds__(256) void ln_kernel(const float* __restrict__ tok,
                                                 const float* __restrict__ g,
                                                 const float* __restrict__ b,
                                                 bf16_t* __restrict__ out) {
    const int n = blockIdx.x;
    const int tid = threadIdx.x;
    const float* row = tok + (size_t)n * 768;
    float x0 = row[tid], x1 = row[tid + 256], x2 = row[tid + 512];
    float s = x0 + x1 + x2;
    float s2 = x0 * x0 + x1 * x1 + x2 * x2;
    #pragma unroll
    for (int off = 32; off; off >>= 1) {
        s += __shfl_xor(s, off);
        s2 += __shfl_xor(s2, off);
    }
    __shared__ float ws1[4], ws2[4];
    int wid = tid >> 6;
    if ((tid & 63) == 0) { ws1[wid] = s; ws2[wid] = s2; }
    __syncthreads();
    s = ws1[0] + ws1[1] + ws1[2] + ws1[3];
    s2 = ws2[0] + ws2[1] + ws2[2] + ws2[3];
    float mu = s * (1.f / 768.f);
    float var = s2 * (1.f / 768.f) - mu * mu;
    float r = rsqrtf(var + 1e-6f);
    bf16_t* orow = out + (size_t)n * 768;
    orow[tid]       = (bf16_t)((x0 - mu) * r * g[tid]       + b[tid]);
    orow[tid + 256] = (bf16_t)((x1 - mu) * r * g[tid + 256] + b[tid + 256]);
    orow[tid + 512] = (bf16_t)((x2 - mu) * r * g[tid + 512] + b[tid + 512]);
}

// ---------------------------------------------------------------------------
// QKV GEMM: bn-fastest grid (36, 32), 128(M)x64(N) tile, BK=64, async dbuf
// glds16 staging with XOR-swizzled LDS. bn: 0..11 = q, 12..23 = k, 24..35 = v.
// ---------------------------------------------------------------------------
__global__ __launch_bounds__(256) void qkv_gemm(const bf16_t* __restrict__ tokb,
                                                const bf16_t* __restrict__ wq,
                                                bf16_t* __restrict__ qb,
                                                bf16_t* __restrict__ kswz,
                                                bf16_t* __restrict__ vswz) {
    const int bn = blockIdx.x;   // 36 n-tiles (64 cols = one head of q/k/v)
    const int bm = blockIdx.y;   // 32 m-tiles (128 tokens)
    const int tid = threadIdx.x;
    const int wid = tid >> 6, lane = tid & 63;
    const int ln = lane & 15, quad = lane >> 4;
    const int wm = wid & 1, wn = wid >> 1;

    __shared__ bf16_t Asw[2][8192];   // 128 rows x 8 chunks x 8 bf16
    __shared__ bf16_t Bsw[2][4096];   // 64 rows x 8 chunks

    f32x4 acc[4][2];
    #pragma unroll
    for (int sm = 0; sm < 4; sm++)
        #pragma unroll
        for (int sn = 0; sn < 2; sn++) acc[sm][sn] = {0.f, 0.f, 0.f, 0.f};

    // staging: per wave, A chunks [wid*256, +256) (4 issues), B [wid*128, +128) (2)
    auto stage = [&](int kb0, int buf) {
        #pragma unroll
        for (int i = 0; i < 4; i++) {
            int L = wid * 256 + i * 64 + lane;
            int r = L >> 3, c = L & 7;
            int gc = c ^ (r & 7);
            glds16(tokb + (size_t)(bm * 128 + r) * 768 + kb0 + gc * 8,
                   Asw[buf] + (wid * 256 + i * 64) * 8);
        }
        #pragma unroll
        for (int i = 0; i < 2; i++) {
            int L = wid * 128 + i * 64 + lane;
            int r = L >> 3, c = L & 7;
            int gc = c ^ (r & 7);
            glds16(wq + (size_t)(bn * 64 + r) * 768 + kb0 + gc * 8,
                   Bsw[buf] + (wid * 128 + i * 64) * 8);
        }
    };

    auto compute = [&](const bf16_t* Ab, const bf16_t* Bb) {
        #pragma unroll
        for (int kk = 0; kk < 2; kk++) {
            const int c = (kk * 4 + quad) ^ (ln & 7);
            bf16x8 af[4], bfr[2];
            #pragma unroll
            for (int sm = 0; sm < 4; sm++) {
                int row = wm * 64 + sm * 16 + ln;
                af[sm] = *(const bf16x8*)(Ab + (row * 8 + c) * 8);
            }
            #pragma unroll
            for (int sn = 0; sn < 2; sn++) {
                int row = wn * 32 + sn * 16 + ln;
                bfr[sn] = *(const bf16x8*)(Bb + (row * 8 + c) * 8);
            }
            #pragma unroll
            for (int sm = 0; sm < 4; sm++)
                #pragma unroll
                for (int sn = 0; sn < 2; sn++)
                    acc[sm][sn] = __builtin_amdgcn_mfma_f32_16x16x32_bf16(af[sm], bfr[sn], acc[sm][sn], 0, 0, 0);
        }
    };

    stage(0, 0);

    for (int s = 0; s < 12; s += 2) {
        __builtin_amdgcn_s_barrier();                 // prev reads of buf1 done
        stage((s + 1) * 64, 1);
        __builtin_amdgcn_s_waitcnt(0x0F76);           // vmcnt(6): buf0 resident
        __builtin_amdgcn_s_barrier();
        compute(Asw[0], Bsw[0]);
        __builtin_amdgcn_s_barrier();                 // prev reads of buf0 done
        if (s + 2 < 12) {
            stage((s + 2) * 64, 0);
            __builtin_amdgcn_s_waitcnt(0x0F76);       // vmcnt(6)
        } else {
            __builtin_amdgcn_s_waitcnt(0x0F70);       // vmcnt(0)
        }
        __builtin_amdgcn_s_barrier();
        compute(Asw[1], Bsw[1]);
    }

    const int sidx = bn / 12;                  // 0=q 1=k 2=v (block-uniform)
    const int head = bn % 12;
    #pragma unroll
    for (int sn = 0; sn < 2; sn++) {
        int dc = wn * 32 + sn * 16 + ln;       // 0..63 within head
        #pragma unroll
        for (int sm = 0; sm < 4; sm++) {
            #pragma unroll
            for (int r = 0; r < 4; r++) {
                int m = bm * 128 + wm * 64 + sm * 16 + quad * 4 + r;   // token = key
                float v = acc[sm][sn][r];
                if (sidx == 0) {
                    qb[((size_t)(head * 4096 + m)) * 64 + dc] = (bf16_t)(v * QSCALE);
                } else if (sidx == 1) {
                    bf16_t val = (bf16_t)v;
                    int kt = m >> 6, sb = (m >> 4) & 3, lnk = m & 15;
                    int half = dc >> 5, quadk = (dc >> 3) & 3, j = dc & 7;
                    int l = quadk * 16 + lnk;
                    kswz[((size_t)(head * 64 + kt)) * 4096 + sb * 1024 + half * 512 + l * 8 + j] = val;
                } else {
                    bf16_t val = (bf16_t)v;
                    int kt = m >> 6, keyl = m & 63;
                    int sblk = keyl >> 4;
                    int mm = sblk >> 1, tb = sblk & 1;
                    int w16 = keyl & 15, qv = w16 >> 2, jj = w16 & 3;
                    int jp = tb * 4 + jj;
                    int db = dc >> 4, lnv = dc & 15;
                    int l = qv * 16 + lnv;
                    vswz[((size_t)(head * 64 + kt)) * 4096 + ((mm * 4 + db) * 64 + l) * 8 + jp] = val;
                }
            }
        }
    }
}

// ---------------------------------------------------------------------------
// Attention v9: v8 + VGPR diet to cross the 64V/64A occupancy step.
//
// Occupancy model (reconciles v1..v8 + m68/m69): unified reg file allocates
// in 64-reg granules per class. v8: 72 VGPR->128 granule + 40 AGPR->64 =
// 192/wave -> 2 waves/SIMD. The ONLY step up is VGPR<=64 AND AGPR<=64 ->
// 128/wave -> 4 waves/SIMD (16 waves/CU, 4 blocks co-resident). At 2
// waves/SIMD every structure ran at the SUM of pipe times (60-72us); at 4
// waves cross-block de-phased waves overlap MFMA/VALU/LDS -> target ~max.
// Diet: minimal-liveness compute (exp/pack consumed per S-tile before the
// next is computed; named fragments) + __launch_bounds__(256,4) to pin the
// allocator at 64 VGPR. AGPR = accO 32 + accL 8 = 40 <= 64. Squeeze is ~8
// transient regs (NOT v4/v7's ~80 live regs) -> low spill risk.
// Tripwires: VGPR_Count must be <=64; WRITE_SIZE must stay ~25MB.
// ---------------------------------------------------------------------------
__global__ __launch_bounds__(256, 4) void attn_partial(const bf16_t* __restrict__ qbuf,
                                                       const bf16_t* __restrict__ kswz,
                                                       const bf16_t* __restrict__ vswz,
                                                       float* __restrict__ raw0,
                                                       float* __restrict__ raw1,
                                                       float* __restrict__ l_part) {
    const int h = blockIdx.y;
    const int chunk = blockIdx.z;
    const int tid = threadIdx.x;
    const int wid = tid >> 6;           // 0..3
    const int lane = tid & 63;
    const int ln = lane & 15, quad = lane >> 4;
    const int qh = wid & 1;             // which 32-query half of the 64q block
    const int kh = wid >> 1;            // which 16-tile key half (block split-K)
    const int q0 = blockIdx.x * 64;

    // staging: K [2 kh][2 buf][2048] at 0, V same at +16384 (32KB total);
    // combine view after syncthreads: [64][68] f32 + l[64] = 17.7KB (fits).
    __shared__ __align__(16) char RAW[32768];
    bf16_t* Kst = (bf16_t*)RAW;
    bf16_t* Vst = (bf16_t*)(RAW + 16384);

    // Q B-frags for this wave's two 16-query groups (32 queries/wave)
    bf16x8 qf[2][2];
    #pragma unroll
    for (int g = 0; g < 2; g++) {
        const int q0g = q0 + qh * 32 + g * 16;
        const bf16_t* qrow = qbuf + ((size_t)h * 4096 + q0g + ln) * 64;
        qf[g][0] = *(const bf16x8*)(qrow + quad * 8);
        qf[g][1] = *(const bf16x8*)(qrow + 32 + quad * 8);
    }

    // all-ones A fragment for the l row-sum MFMA
    bf16x8 ones;
    #pragma unroll
    for (int i = 0; i < 8; i++) ones[i] = (bf16_t)1.0f;

    // this pair's 16-tile (= 32 half-tile) key sub-chunk
    const bf16_t* kg = kswz + (size_t)h * 64 * 4096 + (size_t)(chunk * 32 + kh * 16) * 4096;
    const bf16_t* vg = vswz + (size_t)h * 64 * 4096 + (size_t)(chunk * 32 + kh * 16) * 4096;

    f32x4 accO[2][4];
    f32x4 accL[2];
    #pragma unroll
    for (int g = 0; g < 2; g++) {
        accL[g] = {0.f, 0.f, 0.f, 0.f};
        #pragma unroll
        for (int d = 0; d < 4; d++) accO[g][d] = {0.f, 0.f, 0.f, 0.f};
    }

    // stage one 4KB K + 4KB V half-tile (32 keys) per kh pair; the pair's
    // two waves (qh) each cover half: 2 K + 2 V glds16 per wave
    auto stage = [&](int ht, int buf) {
        const bf16_t* kt_g = kg + (size_t)ht * 2048;
        const bf16_t* vt_g = vg + (size_t)ht * 2048;
        bf16_t* kl = Kst + (kh * 2 + buf) * 2048 + qh * 1024;
        bf16_t* vl = Vst + (kh * 2 + buf) * 2048 + qh * 1024;
        #pragma unroll
        for (int i = 0; i < 2; i++) {
            glds16(kt_g + qh * 1024 + i * 512 + lane * 8, kl + i * 512);
            glds16(vt_g + qh * 1024 + i * 512 + lane * 8, vl + i * 512);
        }
    };

    // one 32-key half-tile; minimal-liveness sequencing: each S-tile's exp
    // + pack is consumed before the next S-tile is produced.
    auto compute = [&](const bf16_t* Kb, const bf16_t* Vb) {
        bf16x8 vf0 = *(const bf16x8*)(Vb + 0 * 512 + lane * 8);
        bf16x8 vf1 = *(const bf16x8*)(Vb + 1 * 512 + lane * 8);
        bf16x8 vf2 = *(const bf16x8*)(Vb + 2 * 512 + lane * 8);
        bf16x8 vf3 = *(const bf16x8*)(Vb + 3 * 512 + lane * 8);
        bf16x8 ka0 = *(const bf16x8*)(Kb + lane * 8);
        bf16x8 ka1 = *(const bf16x8*)(Kb + 512 + lane * 8);
        bf16x8 kb0 = *(const bf16x8*)(Kb + 1024 + lane * 8);
        bf16x8 kb1 = *(const bf16x8*)(Kb + 1536 + lane * 8);
        #pragma unroll
        for (int g = 0; g < 2; g++) {
            f32x4 z = {0.f, 0.f, 0.f, 0.f};
            f32x4 SA = __builtin_amdgcn_mfma_f32_16x16x32_bf16(ka0, qf[g][0], z, 0, 0, 0);
            SA = __builtin_amdgcn_mfma_f32_16x16x32_bf16(ka1, qf[g][1], SA, 0, 0, 0);
            unsigned int u0 = pack_trunc(hwexp2(SA[0]), hwexp2(SA[1]));
            unsigned int u1 = pack_trunc(hwexp2(SA[2]), hwexp2(SA[3]));
            f32x4 SB = __builtin_amdgcn_mfma_f32_16x16x32_bf16(kb0, qf[g][0], z, 0, 0, 0);
            SB = __builtin_amdgcn_mfma_f32_16x16x32_bf16(kb1, qf[g][1], SB, 0, 0, 0);
            unsigned int u2 = pack_trunc(hwexp2(SB[0]), hwexp2(SB[1]));
            unsigned int u3 = pack_trunc(hwexp2(SB[2]), hwexp2(SB[3]));
            uint4v u = {u0, u1, u2, u3};
            bf16x8 pb = __builtin_bit_cast(bf16x8, u);
            accL[g] = __builtin_amdgcn_mfma_f32_16x16x32_bf16(ones, pb, accL[g], 0, 0, 0);
            accO[g][0] = __builtin_amdgcn_mfma_f32_16x16x32_bf16(vf0, pb, accO[g][0], 0, 0, 0);
            accO[g][1] = __builtin_amdgcn_mfma_f32_16x16x32_bf16(vf1, pb, accO[g][1], 0, 0, 0);
            accO[g][2] = __builtin_amdgcn_mfma_f32_16x16x32_bf16(vf2, pb, accO[g][2], 0, 0, 0);
            accO[g][3] = __builtin_amdgcn_mfma_f32_16x16x32_bf16(vf3, pb, accO[g][3], 0, 0, 0);
        }
    };

    stage(0, 0);

    const bf16_t* K0 = Kst + (kh * 2 + 0) * 2048;
    const bf16_t* V0 = Vst + (kh * 2 + 0) * 2048;
    const bf16_t* K1 = Kst + (kh * 2 + 1) * 2048;
    const bf16_t* V1 = Vst + (kh * 2 + 1) * 2048;

    for (int ht = 0; ht < 32; ht += 2) {
        __builtin_amdgcn_s_barrier();                 // prev reads of buf1 done
        stage(ht + 1, 1);
        __builtin_amdgcn_s_waitcnt(0x0F74);           // vmcnt(4): half-tile ht resident
        __builtin_amdgcn_s_barrier();
        compute(K0, V0);
        __builtin_amdgcn_s_barrier();                 // prev reads of buf0 done
        if (ht + 2 < 32) {
            stage(ht + 2, 0);
            __builtin_amdgcn_s_waitcnt(0x0F74);       // vmcnt(4)
        } else {
            __builtin_amdgcn_s_waitcnt(0x0F70);       // vmcnt(0)
        }
        __builtin_amdgcn_s_barrier();
        compute(K1, V1);
    }

    // ---- block-internal split-K combine over LDS ----
    __syncthreads();   // all K/V reads done; RAW reusable
    float* comb  = (float*)RAW;               // [64][68] f32, 17408 B
    float* combl = (float*)(RAW + 17408);     // 64 f32
    if (kh == 1) {
        #pragma unroll
        for (int g = 0; g < 2; g++) {
            const int lq = qh * 32 + g * 16 + ln;
            #pragma unroll
            for (int db = 0; db < 4; db++)
                *(f32x4*)&comb[lq * 68 + db * 16 + quad * 4] = accO[g][db];
            if (quad == 0) combl[lq] = accL[g][0];
        }
    }
    __syncthreads();
    if (kh == 0) {
        float* base = chunk ? raw1 : raw0;
        #pragma unroll
        for (int g = 0; g < 2; g++) {
            const int lq = qh * 32 + g * 16 + ln;
            const int qg = q0 + lq;
            // every lane's accL[g][0] holds l[q=ln] (rows identical for ones-A)
            float lsum = accL[g][0] + combl[lq];
            if (quad == 0) l_part[(size_t)chunk * 49152 + h * 4096 + qg] = lsum;
            float* op = base + (size_t)qg * 768 + h * 64 + quad * 4;
            #pragma unroll
            for (int db = 0; db < 4; db++) {
                f32x4 o = accO[g][db] + *(const f32x4*)&comb[lq * 68 + db * 16 + quad * 4];
                *(f32x4*)(op + db * 16) = o;
            }
        }
    }
}

// ---------------------------------------------------------------------------
// Normalize + combine: out[q,c] = (raw0[q,c] + raw1[q,c]) / (l0[h][q]+l1[h][q])
// raw1 aliases out (d_out scratch) — element-wise read-then-write, safe.
// ---------------------------------------------------------------------------
__global__ __launch_bounds__(256) void norm_kernel(const float* __restrict__ raw0,
                                                   const float* __restrict__ raw1,
                                                   const float* __restrict__ l_part,
                                                   float* __restrict__ out) {
    const int q = blockIdx.x;
    const int tid = threadIdx.x;
    __shared__ float linv[12];
    if (tid < 12)
        linv[tid] = 1.0f / (l_part[tid * 4096 + q] + l_part[49152 + tid * 4096 + q]);
    __syncthreads();
    #pragma unroll
    for (int t = 0; t < 3; t++) {
        int c = tid + t * 256;
        size_t idx = (size_t)q * 768 + c;
        out[idx] = (raw0[idx] + raw1[idx]) * linv[c >> 6];
    }
}

// ---------------------------------------------------------------------------
extern "C" void kernel_launch(void* const* d_in, const int* in_sizes, int n_in,
                              void* d_out, int out_size, void* d_ws, size_t ws_size,
                              hipStream_t stream) {
    const float* x      = (const float*)d_in[0];
    const float* proj_w = (const float*)d_in[1];
    const float* proj_b = (const float*)d_in[2];
    const float* ln_g   = (const float*)d_in[3];
    const float* ln_b   = (const float*)d_in[4];
    const float* qkv_w  = (const float*)d_in[5];
    float* out = (float*)d_out;

    char* ws = (char*)d_ws;
    float*  tok_pre = (float*)(ws + 0);              // 12,582,912 B (reused: raw0)
    bf16_t* tok_b   = (bf16_t*)(ws + 12582912);      //  6,291,456 B
    bf16_t* pw_b    = (bf16_t*)(ws + 18874368);      //    393,216 B (reused: l_part)
    bf16_t* qw_b    = (bf16_t*)(ws + 19267584);      //  3,538,944 B
    bf16_t* qbuf    = (bf16_t*)(ws + 22806528);      //  6,291,456 B
    bf16_t* kswz    = (bf16_t*)(ws + 29097984);      //  6,291,456 B
    bf16_t* vswz    = (bf16_t*)(ws + 35389440);      //  6,291,456 B (total ~41.7 MB)
    float*  raw0    = tok_pre;                       // dead after ln_kernel
    float*  raw1    = out;                           // d_out used as chunk-1 scratch
    float*  l_part  = (float*)pw_b;                  // never used as pw_b anymore

    cvt_kernel<<<1728, 256, 0, stream>>>(qkv_w, qw_b, 442368);
    patch_gemm<<<dim3(12, 64), 256, 0, stream>>>(x, proj_w, proj_b, tok_pre);
    ln_kernel<<<4096, 256, 0, stream>>>(tok_pre, ln_g, ln_b, tok_b);
    qkv_gemm<<<dim3(36, 32), 256, 0, stream>>>(tok_b, qw_b, qbuf, kswz, vswz);
    attn_partial<<<dim3(64, 12, 2), 256, 0, stream>>>(qbuf, kswz, vswz, raw0, raw1, l_part);
    norm_kernel<<<4096, 256, 0, stream>>>(raw0, raw1, l_part, out);
}

// Round 9
// 171.346 us; speedup vs baseline: 1.7601x; 1.0327x over previous
//
#include <hip/hip_runtime.h>
#include <hip/hip_bf16.h>

typedef __bf16 bf16_t;
typedef __attribute__((ext_vector_type(8))) __bf16 bf16x8;
typedef __attribute__((ext_vector_type(4))) __bf16 bf16x4;
typedef __attribute__((ext_vector_type(4))) float f32x4;
typedef __attribute__((ext_vector_type(4))) unsigned int uint4v;

#define QSCALE 0.1803368801111204f  /* 0.125 * log2(e) */

// async global->LDS, 16B per lane; LDS dst = wave-uniform base + lane*16
static __device__ inline void glds16(const bf16_t* g, bf16_t* l) {
    __builtin_amdgcn_global_load_lds(
        (__attribute__((address_space(1))) const void*)g,
        (__attribute__((address_space(3))) void*)l,
        16, 0, 0);
}

// raw hardware v_exp_f32 (input bounded — no libm range/denorm fixup needed)
static __device__ inline float hwexp2(float x) {
#if __has_builtin(__builtin_amdgcn_exp2f)
    return __builtin_amdgcn_exp2f(x);
#else
    float r;
    asm("v_exp_f32 %0, %1" : "=v"(r) : "v"(x));
    return r;
#endif
}

// pack two fp32 -> bf16x2 by truncation (top 16 bits), single v_perm_b32
static __device__ inline unsigned int pack_trunc(float lo, float hi) {
    return __builtin_amdgcn_perm(__builtin_bit_cast(unsigned int, hi),
                                 __builtin_bit_cast(unsigned int, lo),
                                 0x07060302u);
}

// ---------------------------------------------------------------------------
// Fused prep: patch-embed GEMM (by < 64) + qkv_w fp32->bf16 cvt (by >= 64).
// Patch: tok[4096,768] = patches[4096,256] @ proj_w[768,256]^T + b, grid
// slice (12,64). Cvt: 1728 block-equivalents convert 2304x768 fp32 -> bf16;
// memory-bound cvt blocks fill CU bubbles around the compute-bound patch
// blocks, and one launch (+gap) is saved.
// ---------------------------------------------------------------------------
__global__ __launch_bounds__(256) void prep_kernel(const float* __restrict__ x,
                                                   const float* __restrict__ pw,
                                                   const float* __restrict__ pb,
                                                   float* __restrict__ tok,
                                                   const float* __restrict__ qkv_w,
                                                   bf16_t* __restrict__ qw_b) {
    const int tid = threadIdx.x;

    if (blockIdx.y >= 64) {
        // ---- cvt slice: (by-64)*12 + bx in [0, 1728) ----
        int id = (blockIdx.y - 64) * 12 + blockIdx.x;
        int i = id * 256 + tid;                    // < 442368 always (exact)
        float4 v = ((const float4*)qkv_w)[i];
        bf16x4 o = {(bf16_t)v.x, (bf16_t)v.y, (bf16_t)v.z, (bf16_t)v.w};
        ((bf16x4*)qw_b)[i] = o;
        return;
    }

    const int bn = blockIdx.x;   // 12 embed tiles
    const int bm = blockIdx.y;   // 64 token tiles

    __shared__ bf16_t At[64][264];
    __shared__ bf16_t Bt[64][264];

    #pragma unroll
    for (int t = 0; t < 16; t++) {
        int linear = tid + t * 256;
        int ml = linear >> 6;
        int kv = (linear & 63) << 2;
        int n = bm * 64 + ml;
        int pr = n >> 6, pc = n & 63;
        int i = kv >> 4, j = kv & 15;
        float4 v = *(const float4*)(x + (pr * 16 + i) * 1024 + pc * 16 + j);
        bf16x4 o = {(bf16_t)v.x, (bf16_t)v.y, (bf16_t)v.z, (bf16_t)v.w};
        *(bf16x4*)(&At[ml][kv]) = o;
    }
    #pragma unroll
    for (int t = 0; t < 8; t++) {
        int linear = tid + t * 256;
        int nl = linear >> 5;
        int kv = (linear & 31) << 3;
        const float* src = pw + (size_t)(bn * 64 + nl) * 256 + kv;
        float4 v0 = *(const float4*)(src);
        float4 v1 = *(const float4*)(src + 4);
        bf16x8 o = {(bf16_t)v0.x, (bf16_t)v0.y, (bf16_t)v0.z, (bf16_t)v0.w,
                    (bf16_t)v1.x, (bf16_t)v1.y, (bf16_t)v1.z, (bf16_t)v1.w};
        *(bf16x8*)(&Bt[nl][kv]) = o;
    }
    __syncthreads();

    const int lane = tid & 63, wid = tid >> 6, ln = lane & 15, quad = lane >> 4;
    f32x4 acc[4];
    #pragma unroll
    for (int s = 0; s < 4; s++) acc[s] = {0.f, 0.f, 0.f, 0.f};

    #pragma unroll
    for (int kk = 0; kk < 8; kk++) {
        bf16x8 af = *(const bf16x8*)(&At[wid * 16 + ln][kk * 32 + quad * 8]);
        #pragma unroll
        for (int s = 0; s < 4; s++) {
            bf16x8 bfr = *(const bf16x8*)(&Bt[s * 16 + ln][kk * 32 + quad * 8]);
            acc[s] = __builtin_amdgcn_mfma_f32_16x16x32_bf16(af, bfr, acc[s], 0, 0, 0);
        }
    }

    #pragma unroll
    for (int s = 0; s < 4; s++) {
        int e = bn * 64 + s * 16 + ln;
        float bias = pb[e];
        #pragma unroll
        for (int r = 0; r < 4; r++) {
            int m = bm * 64 + wid * 16 + quad * 4 + r;
            tok[(size_t)m * 768 + e] = acc[s][r] + bias;
        }
    }
}

// ---------------------------------------------------------------------------
// LayerNorm per token (768), fp32 stats, bf16 out.
// ---------------------------------------------------------------------------
__global__ __launch_bounds__(256) void ln_kernel(const float* __restrict__ tok,
                                                 const float* __restrict__ g,
                                                 const float* __restrict__ b,
                                                 bf16_t* __restrict__ out) {
    const int n = blockIdx.x;
    const int tid = threadIdx.x;
    const float* row = tok + (size_t)n * 768;
    float x0 = row[tid], x1 = row[tid + 256], x2 = row[tid + 512];
    float s = x0 + x1 + x2;
    float s2 = x0 * x0 + x1 * x1 + x2 * x2;
    #pragma unroll
    for (int off = 32; off; off >>= 1) {
        s += __shfl_xor(s, off);
        s2 += __shfl_xor(s2, off);
    }
    __shared__ float ws1[4], ws2[4];
    int wid = tid >> 6;
    if ((tid & 63) == 0) { ws1[wid] = s; ws2[wid] = s2; }
    __syncthreads();
    s = ws1[0] + ws1[1] + ws1[2] + ws1[3];
    s2 = ws2[0] + ws2[1] + ws2[2] + ws2[3];
    float mu = s * (1.f / 768.f);
    float var = s2 * (1.f / 768.f) - mu * mu;
    float r = rsqrtf(var + 1e-6f);
    bf16_t* orow = out + (size_t)n * 768;
    orow[tid]       = (bf16_t)((x0 - mu) * r * g[tid]       + b[tid]);
    orow[tid + 256] = (bf16_t)((x1 - mu) * r * g[tid + 256] + b[tid + 256]);
    orow[tid + 512] = (bf16_t)((x2 - mu) * r * g[tid + 512] + b[tid + 512]);
}

// ---------------------------------------------------------------------------
// QKV GEMM: bn-fastest grid (36, 32), 128(M)x64(N) tile, BK=64, async dbuf
// glds16 staging with XOR-swizzled LDS. bn: 0..11 = q, 12..23 = k, 24..35 = v.
// ---------------------------------------------------------------------------
__global__ __launch_bounds__(256) void qkv_gemm(const bf16_t* __restrict__ tokb,
                                                const bf16_t* __restrict__ wq,
                                                bf16_t* __restrict__ qb,
                                                bf16_t* __restrict__ kswz,
                                                bf16_t* __restrict__ vswz) {
    const int bn = blockIdx.x;   // 36 n-tiles (64 cols = one head of q/k/v)
    const int bm = blockIdx.y;   // 32 m-tiles (128 tokens)
    const int tid = threadIdx.x;
    const int wid = tid >> 6, lane = tid & 63;
    const int ln = lane & 15, quad = lane >> 4;
    const int wm = wid & 1, wn = wid >> 1;

    __shared__ bf16_t Asw[2][8192];   // 128 rows x 8 chunks x 8 bf16
    __shared__ bf16_t Bsw[2][4096];   // 64 rows x 8 chunks

    f32x4 acc[4][2];
    #pragma unroll
    for (int sm = 0; sm < 4; sm++)
        #pragma unroll
        for (int sn = 0; sn < 2; sn++) acc[sm][sn] = {0.f, 0.f, 0.f, 0.f};

    // staging: per wave, A chunks [wid*256, +256) (4 issues), B [wid*128, +128) (2)
    auto stage = [&](int kb0, int buf) {
        #pragma unroll
        for (int i = 0; i < 4; i++) {
            int L = wid * 256 + i * 64 + lane;
            int r = L >> 3, c = L & 7;
            int gc = c ^ (r & 7);
            glds16(tokb + (size_t)(bm * 128 + r) * 768 + kb0 + gc * 8,
                   Asw[buf] + (wid * 256 + i * 64) * 8);
        }
        #pragma unroll
        for (int i = 0; i < 2; i++) {
            int L = wid * 128 + i * 64 + lane;
            int r = L >> 3, c = L & 7;
            int gc = c ^ (r & 7);
            glds16(wq + (size_t)(bn * 64 + r) * 768 + kb0 + gc * 8,
                   Bsw[buf] + (wid * 128 + i * 64) * 8);
        }
    };

    auto compute = [&](const bf16_t* Ab, const bf16_t* Bb) {
        #pragma unroll
        for (int kk = 0; kk < 2; kk++) {
            const int c = (kk * 4 + quad) ^ (ln & 7);
            bf16x8 af[4], bfr[2];
            #pragma unroll
            for (int sm = 0; sm < 4; sm++) {
                int row = wm * 64 + sm * 16 + ln;
                af[sm] = *(const bf16x8*)(Ab + (row * 8 + c) * 8);
            }
            #pragma unroll
            for (int sn = 0; sn < 2; sn++) {
                int row = wn * 32 + sn * 16 + ln;
                bfr[sn] = *(const bf16x8*)(Bb + (row * 8 + c) * 8);
            }
            #pragma unroll
            for (int sm = 0; sm < 4; sm++)
                #pragma unroll
                for (int sn = 0; sn < 2; sn++)
                    acc[sm][sn] = __builtin_amdgcn_mfma_f32_16x16x32_bf16(af[sm], bfr[sn], acc[sm][sn], 0, 0, 0);
        }
    };

    stage(0, 0);

    for (int s = 0; s < 12; s += 2) {
        __builtin_amdgcn_s_barrier();                 // prev reads of buf1 done
        stage((s + 1) * 64, 1);
        __builtin_amdgcn_s_waitcnt(0x0F76);           // vmcnt(6): buf0 resident
        __builtin_amdgcn_s_barrier();
        compute(Asw[0], Bsw[0]);
        __builtin_amdgcn_s_barrier();                 // prev reads of buf0 done
        if (s + 2 < 12) {
            stage((s + 2) * 64, 0);
            __builtin_amdgcn_s_waitcnt(0x0F76);       // vmcnt(6)
        } else {
            __builtin_amdgcn_s_waitcnt(0x0F70);       // vmcnt(0)
        }
        __builtin_amdgcn_s_barrier();
        compute(Asw[1], Bsw[1]);
    }

    const int sidx = bn / 12;                  // 0=q 1=k 2=v (block-uniform)
    const int head = bn % 12;
    #pragma unroll
    for (int sn = 0; sn < 2; sn++) {
        int dc = wn * 32 + sn * 16 + ln;       // 0..63 within head
        #pragma unroll
        for (int sm = 0; sm < 4; sm++) {
            #pragma unroll
            for (int r = 0; r < 4; r++) {
                int m = bm * 128 + wm * 64 + sm * 16 + quad * 4 + r;   // token = key
                float v = acc[sm][sn][r];
                if (sidx == 0) {
                    qb[((size_t)(head * 4096 + m)) * 64 + dc] = (bf16_t)(v * QSCALE);
                } else if (sidx == 1) {
                    bf16_t val = (bf16_t)v;
                    int kt = m >> 6, sb = (m >> 4) & 3, lnk = m & 15;
                    int half = dc >> 5, quadk = (dc >> 3) & 3, j = dc & 7;
                    int l = quadk * 16 + lnk;
                    kswz[((size_t)(head * 64 + kt)) * 4096 + sb * 1024 + half * 512 + l * 8 + j] = val;
                } else {
                    bf16_t val = (bf16_t)v;
                    int kt = m >> 6, keyl = m & 63;
                    int sblk = keyl >> 4;
                    int mm = sblk >> 1, tb = sblk & 1;
                    int w16 = keyl & 15, qv = w16 >> 2, jj = w16 & 3;
                    int jp = tb * 4 + jj;
                    int db = dc >> 4, lnv = dc & 15;
                    int l = qv * 16 + lnv;
                    vswz[((size_t)(head * 64 + kt)) * 4096 + ((mm * 4 + db) * 64 + l) * 8 + jp] = val;
                }
            }
        }
    }
}

// ---------------------------------------------------------------------------
// Attention v10 = v9 core (32q/wave, 64-reg budget, half-tile glds dbuf,
// kh split-K pair) with split-K-ACROSS-BLOCKS REMOVED: each block now covers
// all 4096 keys for its 64 queries (kh pair: 2048 keys each, 64 half-tiles),
// combines partials in LDS and NORMALIZES INLINE, writing final fp32 out.
// Eliminates norm_kernel + l_part + 38MB raw traffic + one launch gap.
// Grid (64,12)=768 = 3 blocks/CU, fully co-resident (4 fit) -> no tail.
// Tripwires: VGPR_Count <= 64, WRITE_SIZE ~13MB.
// ---------------------------------------------------------------------------
__global__ __launch_bounds__(256, 4) void attn_full(const bf16_t* __restrict__ qbuf,
                                                    const bf16_t* __restrict__ kswz,
                                                    const bf16_t* __restrict__ vswz,
                                                    float* __restrict__ out) {
    const int h = blockIdx.y;
    const int tid = threadIdx.x;
    const int wid = tid >> 6;           // 0..3
    const int lane = tid & 63;
    const int ln = lane & 15, quad = lane >> 4;
    const int qh = wid & 1;             // which 32-query half of the 64q block
    const int kh = wid >> 1;            // which 2048-key half (block split-K)
    const int q0 = blockIdx.x * 64;

    // staging: K [2 kh][2 buf][2048] at 0, V same at +16384 (32KB total);
    // combine view after syncthreads: [64][68] f32 + l[64] = 17.7KB (fits).
    __shared__ __align__(16) char RAW[32768];
    bf16_t* Kst = (bf16_t*)RAW;
    bf16_t* Vst = (bf16_t*)(RAW + 16384);

    // Q B-frags for this wave's two 16-query groups (32 queries/wave)
    bf16x8 qf[2][2];
    #pragma unroll
    for (int g = 0; g < 2; g++) {
        const int q0g = q0 + qh * 32 + g * 16;
        const bf16_t* qrow = qbuf + ((size_t)h * 4096 + q0g + ln) * 64;
        qf[g][0] = *(const bf16x8*)(qrow + quad * 8);
        qf[g][1] = *(const bf16x8*)(qrow + 32 + quad * 8);
    }

    // all-ones A fragment for the l row-sum MFMA
    bf16x8 ones;
    #pragma unroll
    for (int i = 0; i < 8; i++) ones[i] = (bf16_t)1.0f;

    // this pair's 32-tile (= 64 half-tile) key sub-range
    const bf16_t* kg = kswz + (size_t)h * 64 * 4096 + (size_t)(kh * 32) * 4096;
    const bf16_t* vg = vswz + (size_t)h * 64 * 4096 + (size_t)(kh * 32) * 4096;

    f32x4 accO[2][4];
    f32x4 accL[2];
    #pragma unroll
    for (int g = 0; g < 2; g++) {
        accL[g] = {0.f, 0.f, 0.f, 0.f};
        #pragma unroll
        for (int d = 0; d < 4; d++) accO[g][d] = {0.f, 0.f, 0.f, 0.f};
    }

    // stage one 4KB K + 4KB V half-tile (32 keys) per kh pair; the pair's
    // two waves (qh) each cover half: 2 K + 2 V glds16 per wave
    auto stage = [&](int ht, int buf) {
        const bf16_t* kt_g = kg + (size_t)ht * 2048;
        const bf16_t* vt_g = vg + (size_t)ht * 2048;
        bf16_t* kl = Kst + (kh * 2 + buf) * 2048 + qh * 1024;
        bf16_t* vl = Vst + (kh * 2 + buf) * 2048 + qh * 1024;
        #pragma unroll
        for (int i = 0; i < 2; i++) {
            glds16(kt_g + qh * 1024 + i * 512 + lane * 8, kl + i * 512);
            glds16(vt_g + qh * 1024 + i * 512 + lane * 8, vl + i * 512);
        }
    };

    // one 32-key half-tile; minimal-liveness sequencing: each S-tile's exp
    // + pack is consumed before the next S-tile is produced.
    auto compute = [&](const bf16_t* Kb, const bf16_t* Vb) {
        bf16x8 vf0 = *(const bf16x8*)(Vb + 0 * 512 + lane * 8);
        bf16x8 vf1 = *(const bf16x8*)(Vb + 1 * 512 + lane * 8);
        bf16x8 vf2 = *(const bf16x8*)(Vb + 2 * 512 + lane * 8);
        bf16x8 vf3 = *(const bf16x8*)(Vb + 3 * 512 + lane * 8);
        bf16x8 ka0 = *(const bf16x8*)(Kb + lane * 8);
        bf16x8 ka1 = *(const bf16x8*)(Kb + 512 + lane * 8);
        bf16x8 kb0 = *(const bf16x8*)(Kb + 1024 + lane * 8);
        bf16x8 kb1 = *(const bf16x8*)(Kb + 1536 + lane * 8);
        #pragma unroll
        for (int g = 0; g < 2; g++) {
            f32x4 z = {0.f, 0.f, 0.f, 0.f};
            f32x4 SA = __builtin_amdgcn_mfma_f32_16x16x32_bf16(ka0, qf[g][0], z, 0, 0, 0);
            SA = __builtin_amdgcn_mfma_f32_16x16x32_bf16(ka1, qf[g][1], SA, 0, 0, 0);
            unsigned int u0 = pack_trunc(hwexp2(SA[0]), hwexp2(SA[1]));
            unsigned int u1 = pack_trunc(hwexp2(SA[2]), hwexp2(SA[3]));
            f32x4 SB = __builtin_amdgcn_mfma_f32_16x16x32_bf16(kb0, qf[g][0], z, 0, 0, 0);
            SB = __builtin_amdgcn_mfma_f32_16x16x32_bf16(kb1, qf[g][1], SB, 0, 0, 0);
            unsigned int u2 = pack_trunc(hwexp2(SB[0]), hwexp2(SB[1]));
            unsigned int u3 = pack_trunc(hwexp2(SB[2]), hwexp2(SB[3]));
            uint4v u = {u0, u1, u2, u3};
            bf16x8 pb = __builtin_bit_cast(bf16x8, u);
            accL[g] = __builtin_amdgcn_mfma_f32_16x16x32_bf16(ones, pb, accL[g], 0, 0, 0);
            accO[g][0] = __builtin_amdgcn_mfma_f32_16x16x32_bf16(vf0, pb, accO[g][0], 0, 0, 0);
            accO[g][1] = __builtin_amdgcn_mfma_f32_16x16x32_bf16(vf1, pb, accO[g][1], 0, 0, 0);
            accO[g][2] = __builtin_amdgcn_mfma_f32_16x16x32_bf16(vf2, pb, accO[g][2], 0, 0, 0);
            accO[g][3] = __builtin_amdgcn_mfma_f32_16x16x32_bf16(vf3, pb, accO[g][3], 0, 0, 0);
        }
    };

    stage(0, 0);

    const bf16_t* K0 = Kst + (kh * 2 + 0) * 2048;
    const bf16_t* V0 = Vst + (kh * 2 + 0) * 2048;
    const bf16_t* K1 = Kst + (kh * 2 + 1) * 2048;
    const bf16_t* V1 = Vst + (kh * 2 + 1) * 2048;

    for (int ht = 0; ht < 64; ht += 2) {
        __builtin_amdgcn_s_barrier();                 // prev reads of buf1 done
        stage(ht + 1, 1);
        __builtin_amdgcn_s_waitcnt(0x0F74);           // vmcnt(4): half-tile ht resident
        __builtin_amdgcn_s_barrier();
        compute(K0, V0);
        __builtin_amdgcn_s_barrier();                 // prev reads of buf0 done
        if (ht + 2 < 64) {
            stage(ht + 2, 0);
            __builtin_amdgcn_s_waitcnt(0x0F74);       // vmcnt(4)
        } else {
            __builtin_amdgcn_s_waitcnt(0x0F70);       // vmcnt(0)
        }
        __builtin_amdgcn_s_barrier();
        compute(K1, V1);
    }

    // ---- block-internal split-K combine + inline normalize ----
    __syncthreads();   // all K/V reads done; RAW reusable
    float* comb  = (float*)RAW;               // [64][68] f32, 17408 B
    float* combl = (float*)(RAW + 17408);     // 64 f32
    if (kh == 1) {
        #pragma unroll
        for (int g = 0; g < 2; g++) {
            const int lq = qh * 32 + g * 16 + ln;
            #pragma unroll
            for (int db = 0; db < 4; db++)
                *(f32x4*)&comb[lq * 68 + db * 16 + quad * 4] = accO[g][db];
            if (quad == 0) combl[lq] = accL[g][0];
        }
    }
    __syncthreads();
    if (kh == 0) {
        #pragma unroll
        for (int g = 0; g < 2; g++) {
            const int lq = qh * 32 + g * 16 + ln;
            const int qg = q0 + lq;
            // every lane's accL[g][0] holds l[q=ln] (rows identical for ones-A)
            float inv = 1.0f / (accL[g][0] + combl[lq]);
            float* op = out + (size_t)qg * 768 + h * 64 + quad * 4;
            #pragma unroll
            for (int db = 0; db < 4; db++) {
                f32x4 o = (accO[g][db] + *(const f32x4*)&comb[lq * 68 + db * 16 + quad * 4]);
                o *= inv;
                *(f32x4*)(op + db * 16) = o;
            }
        }
    }
}

// ---------------------------------------------------------------------------
extern "C" void kernel_launch(void* const* d_in, const int* in_sizes, int n_in,
                              void* d_out, int out_size, void* d_ws, size_t ws_size,
                              hipStream_t stream) {
    const float* x      = (const float*)d_in[0];
    const float* proj_w = (const float*)d_in[1];
    const float* proj_b = (const float*)d_in[2];
    const float* ln_g   = (const float*)d_in[3];
    const float* ln_b   = (const float*)d_in[4];
    const float* qkv_w  = (const float*)d_in[5];
    float* out = (float*)d_out;

    char* ws = (char*)d_ws;
    float*  tok_pre = (float*)(ws + 0);              // 12,582,912 B
    bf16_t* tok_b   = (bf16_t*)(ws + 12582912);      //  6,291,456 B
    bf16_t* qw_b    = (bf16_t*)(ws + 18874368);      //  3,538,944 B
    bf16_t* qbuf    = (bf16_t*)(ws + 22413312);      //  6,291,456 B
    bf16_t* kswz    = (bf16_t*)(ws + 28704768);      //  6,291,456 B
    bf16_t* vswz    = (bf16_t*)(ws + 34996224);      //  6,291,456 B (total ~41.3 MB)

    // patch tiles (by<64) + qkv_w cvt (by in [64,208))
    prep_kernel<<<dim3(12, 208), 256, 0, stream>>>(x, proj_w, proj_b, tok_pre, qkv_w, qw_b);
    ln_kernel<<<4096, 256, 0, stream>>>(tok_pre, ln_g, ln_b, tok_b);
    qkv_gemm<<<dim3(36, 32), 256, 0, stream>>>(tok_b, qw_b, qbuf, kswz, vswz);
    attn_full<<<dim3(64, 12), 256, 0, stream>>>(qbuf, kswz, vswz, out);
}